// Round 2
// baseline (12032.071 us; speedup 1.0000x reference)
//
#include <hip/hip_runtime.h>

#define N_NODES 50000
#define N_EDGES 800000
#define HD      128
#define NG      64
#define NLAYER  3
#define INV_CUTOFF 0.2f

__device__ __forceinline__ float silu_f(float x) {
    return x / (1.0f + __expf(-x));
}

// ---------------------------------------------------------------------------
// h[n] = emb[x[n]]   (N*H floats, float4-vectorized)
// ---------------------------------------------------------------------------
__global__ __launch_bounds__(256) void embed_kernel(
    const int* __restrict__ x, const float* __restrict__ emb,
    float* __restrict__ h)
{
    int i = blockIdx.x * 256 + threadIdx.x;      // float4 index, total N*32
    int n = i >> 5;
    int q = (i & 31) << 2;
    *(float4*)&h[(size_t)n * HD + q] =
        *(const float4*)&emb[(size_t)x[n] * HD + q];
}

// ---------------------------------------------------------------------------
// Fused edge MLP + scatter:
//   m = silu(silu([h[row]|h[col]|ea|d] @ W1 + b1) @ W2 + b2); agg[row] += m
// Tile: 128 edges x 128 cols, 256 threads, 8x8 per-thread micro-tile.
// LDS 65.5 KB -> 2 blocks/CU (2 waves/SIMD). GEMM2 runs in two 64-col
// passes so Ys is only [64][128].
// ---------------------------------------------------------------------------
__global__ __launch_bounds__(256) void edge_kernel(
    const float* __restrict__ h, const int* __restrict__ ei,
    const float* __restrict__ ew, const float* __restrict__ ea,
    const float* __restrict__ W1, const float* __restrict__ b1,
    const float* __restrict__ W2, const float* __restrict__ b2,
    float* __restrict__ agg)
{
    __shared__ float Ws[32 * HD];     // 16 KB  weight K-chunk
    __shared__ float As[32 * HD];     // 16 KB  A K-chunk, [k][e] transposed
    __shared__ float Ys[64 * HD];     // 32 KB  y1 half, [c&63][e] swizzled
    __shared__ int   srow[128], scol[128];
    __shared__ float sd[128];

    const int tid = threadIdx.x;
    const int e0  = blockIdx.x * 128;

    if (tid < 128) {
        int e = e0 + tid;
        srow[tid] = ei[e];
        scol[tid] = ei[N_EDGES + e];
        sd[tid]   = ew[e] * INV_CUTOFF;
    }
    __syncthreads();

    const int tc = (tid & 15) << 3;   // col offset 0..120
    const int tr = (tid >> 4) << 3;   // row (edge) offset 0..120
    const int kq = (tid & 7) << 2;    // staging: float4 offset within 32-chunk

    // staging edge ids for this thread (fixed across chunks)
    int eA[4], rA[4], cA[4];
#pragma unroll
    for (int i = 0; i < 4; ++i) {
        eA[i] = (tid >> 3) + (i << 5);
        rA[i] = srow[eA[i]];
        cA[i] = scol[eA[i]];
    }

    float acc[8][8];
#pragma unroll
    for (int i = 0; i < 8; ++i)
#pragma unroll
        for (int j = 0; j < 8; ++j) acc[i][j] = 0.0f;

    // ---- GEMM1: K = 384 (12 chunks of 32); k row 384 (d term) in epilogue
#pragma unroll 1
    for (int ch = 0; ch < 12; ++ch) {
        // stage W1 chunk [32][128]
#pragma unroll
        for (int i = 0; i < 4; ++i) {
            int flat = tid + (i << 8);
            int wk = flat >> 5;
            int wj = (flat & 31) << 2;
            *(float4*)&Ws[wk * HD + wj] =
                *(const float4*)&W1[(size_t)(ch * 32 + wk) * HD + wj];
        }
        // stage A chunk transposed: As[k][e]
#pragma unroll
        for (int i = 0; i < 4; ++i) {
            const float* src;
            if (ch < 4)      src = h  + (size_t)rA[i] * HD + (ch << 5) + kq;
            else if (ch < 8) src = h  + (size_t)cA[i] * HD + ((ch - 4) << 5) + kq;
            else             src = ea + (size_t)(e0 + eA[i]) * HD + ((ch - 8) << 5) + kq;
            float4 v = *(const float4*)src;
            As[(kq + 0) * HD + eA[i]] = v.x;
            As[(kq + 1) * HD + eA[i]] = v.y;
            As[(kq + 2) * HD + eA[i]] = v.z;
            As[(kq + 3) * HD + eA[i]] = v.w;
        }
        __syncthreads();
#pragma unroll 8
        for (int k = 0; k < 32; ++k) {
            float a[8], b[8];
            *(float4*)&a[0] = *(float4*)&As[k * HD + tr];
            *(float4*)&a[4] = *(float4*)&As[k * HD + tr + 4];
            *(float4*)&b[0] = *(float4*)&Ws[k * HD + tc];
            *(float4*)&b[4] = *(float4*)&Ws[k * HD + tc + 4];
#pragma unroll
            for (int i = 0; i < 8; ++i)
#pragma unroll
                for (int j = 0; j < 8; ++j)
                    acc[i][j] = fmaf(a[i], b[j], acc[i][j]);
        }
        __syncthreads();
    }

    // ---- epilogue 1: + b1 + d*W1[384], silu -> acc (registers)
    {
        float bb[8], wd[8];
        *(float4*)&bb[0] = *(const float4*)&b1[tc];
        *(float4*)&bb[4] = *(const float4*)&b1[tc + 4];
        *(float4*)&wd[0] = *(const float4*)&W1[(size_t)384 * HD + tc];
        *(float4*)&wd[4] = *(const float4*)&W1[(size_t)384 * HD + tc + 4];
#pragma unroll
        for (int i = 0; i < 8; ++i) {
            float d = sd[tr + i];
#pragma unroll
            for (int j = 0; j < 8; ++j) {
                float v = acc[i][j] + bb[j] + d * wd[j];
                acc[i][j] = silu_f(v);
            }
        }
    }

    // ---- GEMM2: y2 = y1 @ W2, K = 128, two 64-col passes through Ys
    float acc2[8][8];
#pragma unroll
    for (int i = 0; i < 8; ++i)
#pragma unroll
        for (int j = 0; j < 8; ++j) acc2[i][j] = 0.0f;

#pragma unroll 1
    for (int pass = 0; pass < 2; ++pass) {
        // store this pass's y1 columns (threads owning cols [pass*64, pass*64+64))
        if ((tc >> 6) == pass) {
#pragma unroll
            for (int j = 0; j < 8; ++j) {
                int r = tc + j;                       // global y1 column
                int base = tr ^ (((r >> 3) & 3) << 3);
                float4 v0 = make_float4(acc[0][j], acc[1][j], acc[2][j], acc[3][j]);
                float4 v1 = make_float4(acc[4][j], acc[5][j], acc[6][j], acc[7][j]);
                *(float4*)&Ys[(r & 63) * HD + base]     = v0;
                *(float4*)&Ys[(r & 63) * HD + base + 4] = v1;
            }
        }
#pragma unroll 1
        for (int ch = 0; ch < 2; ++ch) {
            // stage W2 rows [pass*64 + ch*32, +32)
#pragma unroll
            for (int i = 0; i < 4; ++i) {
                int flat = tid + (i << 8);
                int wk = flat >> 5;
                int wj = (flat & 31) << 2;
                *(float4*)&Ws[wk * HD + wj] =
                    *(const float4*)&W2[(size_t)(pass * 64 + ch * 32 + wk) * HD + wj];
            }
            __syncthreads();
#pragma unroll 8
            for (int k = 0; k < 32; ++k) {
                int kl = ch * 32 + k;                 // Ys row (= global col & 63)
                int base = tr ^ (((kl >> 3) & 3) << 3);
                float a[8], b[8];
                *(float4*)&a[0] = *(float4*)&Ys[kl * HD + base];
                *(float4*)&a[4] = *(float4*)&Ys[kl * HD + base + 4];
                *(float4*)&b[0] = *(float4*)&Ws[k * HD + tc];
                *(float4*)&b[4] = *(float4*)&Ws[k * HD + tc + 4];
#pragma unroll
                for (int i = 0; i < 8; ++i)
#pragma unroll
                    for (int j = 0; j < 8; ++j)
                        acc2[i][j] = fmaf(a[i], b[j], acc2[i][j]);
            }
            __syncthreads();   // also protects next pass's Ys store / Ws re-stage
        }
    }

    // ---- epilogue 2: silu, native-fp32 atomic scatter into agg[row]
    {
        float bb[8];
        *(float4*)&bb[0] = *(const float4*)&b2[tc];
        *(float4*)&bb[4] = *(const float4*)&b2[tc + 4];
#pragma unroll
        for (int i = 0; i < 8; ++i) {
            float* dst = agg + (size_t)srow[tr + i] * HD + tc;
#pragma unroll
            for (int j = 0; j < 8; ++j) {
                unsafeAtomicAdd(&dst[j], silu_f(acc2[i][j] + bb[j]));
            }
        }
    }
}

// ---------------------------------------------------------------------------
// Fused node MLP + residual: h += silu([h|agg] @ nw1 + nb1) @ nw2 + nb2
// Same tile structure as edge_kernel (two-pass GEMM2, 64 KB LDS, 2 blocks/CU);
// exclusive row ownership so the residual update needs no atomics.
// ---------------------------------------------------------------------------
__global__ __launch_bounds__(256) void node_kernel(
    float* __restrict__ h, const float* __restrict__ agg,
    const float* __restrict__ W1, const float* __restrict__ b1,
    const float* __restrict__ W2, const float* __restrict__ b2)
{
    __shared__ float Ws[32 * HD];
    __shared__ float As[32 * HD];
    __shared__ float Ys[64 * HD];

    const int tid = threadIdx.x;
    const int n0  = blockIdx.x * 128;

    const int tc = (tid & 15) << 3;
    const int tr = (tid >> 4) << 3;
    const int kq = (tid & 7) << 2;

    int nA[4];
#pragma unroll
    for (int i = 0; i < 4; ++i) {
        int n = n0 + (tid >> 3) + (i << 5);
        nA[i] = n < N_NODES ? n : (N_NODES - 1);
    }

    float acc[8][8];
#pragma unroll
    for (int i = 0; i < 8; ++i)
#pragma unroll
        for (int j = 0; j < 8; ++j) acc[i][j] = 0.0f;

    // ---- GEMM1: K = 256 (8 chunks of 32): 0-3 from h, 4-7 from agg
#pragma unroll 1
    for (int ch = 0; ch < 8; ++ch) {
#pragma unroll
        for (int i = 0; i < 4; ++i) {
            int flat = tid + (i << 8);
            int wk = flat >> 5;
            int wj = (flat & 31) << 2;
            *(float4*)&Ws[wk * HD + wj] =
                *(const float4*)&W1[(size_t)(ch * 32 + wk) * HD + wj];
        }
#pragma unroll
        for (int i = 0; i < 4; ++i) {
            const float* src = (ch < 4)
                ? h   + (size_t)nA[i] * HD + (ch << 5) + kq
                : agg + (size_t)nA[i] * HD + ((ch - 4) << 5) + kq;
            float4 v = *(const float4*)src;
            int e = (tid >> 3) + (i << 5);
            As[(kq + 0) * HD + e] = v.x;
            As[(kq + 1) * HD + e] = v.y;
            As[(kq + 2) * HD + e] = v.z;
            As[(kq + 3) * HD + e] = v.w;
        }
        __syncthreads();
#pragma unroll 8
        for (int k = 0; k < 32; ++k) {
            float a[8], b[8];
            *(float4*)&a[0] = *(float4*)&As[k * HD + tr];
            *(float4*)&a[4] = *(float4*)&As[k * HD + tr + 4];
            *(float4*)&b[0] = *(float4*)&Ws[k * HD + tc];
            *(float4*)&b[4] = *(float4*)&Ws[k * HD + tc + 4];
#pragma unroll
            for (int i = 0; i < 8; ++i)
#pragma unroll
                for (int j = 0; j < 8; ++j)
                    acc[i][j] = fmaf(a[i], b[j], acc[i][j]);
        }
        __syncthreads();
    }

    // ---- epilogue 1: silu -> acc (registers)
    {
        float bb[8];
        *(float4*)&bb[0] = *(const float4*)&b1[tc];
        *(float4*)&bb[4] = *(const float4*)&b1[tc + 4];
#pragma unroll
        for (int i = 0; i < 8; ++i)
#pragma unroll
            for (int j = 0; j < 8; ++j)
                acc[i][j] = silu_f(acc[i][j] + bb[j]);
    }

    // ---- GEMM2: K = 128, two 64-col passes
    float acc2[8][8];
#pragma unroll
    for (int i = 0; i < 8; ++i)
#pragma unroll
        for (int j = 0; j < 8; ++j) acc2[i][j] = 0.0f;

#pragma unroll 1
    for (int pass = 0; pass < 2; ++pass) {
        if ((tc >> 6) == pass) {
#pragma unroll
            for (int j = 0; j < 8; ++j) {
                int r = tc + j;
                int base = tr ^ (((r >> 3) & 3) << 3);
                float4 v0 = make_float4(acc[0][j], acc[1][j], acc[2][j], acc[3][j]);
                float4 v1 = make_float4(acc[4][j], acc[5][j], acc[6][j], acc[7][j]);
                *(float4*)&Ys[(r & 63) * HD + base]     = v0;
                *(float4*)&Ys[(r & 63) * HD + base + 4] = v1;
            }
        }
#pragma unroll 1
        for (int ch = 0; ch < 2; ++ch) {
#pragma unroll
            for (int i = 0; i < 4; ++i) {
                int flat = tid + (i << 8);
                int wk = flat >> 5;
                int wj = (flat & 31) << 2;
                *(float4*)&Ws[wk * HD + wj] =
                    *(const float4*)&W2[(size_t)(pass * 64 + ch * 32 + wk) * HD + wj];
            }
            __syncthreads();
#pragma unroll 8
            for (int k = 0; k < 32; ++k) {
                int kl = ch * 32 + k;
                int base = tr ^ (((kl >> 3) & 3) << 3);
                float a[8], b[8];
                *(float4*)&a[0] = *(float4*)&Ys[kl * HD + base];
                *(float4*)&a[4] = *(float4*)&Ys[kl * HD + base + 4];
                *(float4*)&b[0] = *(float4*)&Ws[k * HD + tc];
                *(float4*)&b[4] = *(float4*)&Ws[k * HD + tc + 4];
#pragma unroll
                for (int i = 0; i < 8; ++i)
#pragma unroll
                    for (int j = 0; j < 8; ++j)
                        acc2[i][j] = fmaf(a[i], b[j], acc2[i][j]);
            }
            __syncthreads();
        }
    }

    // ---- epilogue 2: residual add (exclusive ownership, plain RMW)
    {
        float bb[8];
        *(float4*)&bb[0] = *(const float4*)&b2[tc];
        *(float4*)&bb[4] = *(const float4*)&b2[tc + 4];
#pragma unroll
        for (int i = 0; i < 8; ++i) {
            int n = n0 + tr + i;
            if (n < N_NODES) {
                float* dst = h + (size_t)n * HD + tc;
                float4 o0 = *(float4*)&dst[0];
                float4 o1 = *(float4*)&dst[4];
                o0.x += acc2[i][0] + bb[0];
                o0.y += acc2[i][1] + bb[1];
                o0.z += acc2[i][2] + bb[2];
                o0.w += acc2[i][3] + bb[3];
                o1.x += acc2[i][4] + bb[4];
                o1.y += acc2[i][5] + bb[5];
                o1.z += acc2[i][6] + bb[6];
                o1.w += acc2[i][7] + bb[7];
                *(float4*)&dst[0] = o0;
                *(float4*)&dst[4] = o1;
            }
        }
    }
}

// ---------------------------------------------------------------------------
// Per-graph mean pool (batch sorted) -> relu -> @ linw + linb
// One block per graph.
// ---------------------------------------------------------------------------
__global__ __launch_bounds__(256) void pool_kernel(
    const float* __restrict__ h, const int* __restrict__ batch,
    const float* __restrict__ linw, const float* __restrict__ linb,
    float* __restrict__ out)
{
    const int g   = blockIdx.x;
    const int tid = threadIdx.x;

    // lower_bound(batch, g) / lower_bound(batch, g+1)
    int lo = 0, hi = N_NODES;
    while (lo < hi) { int mid = (lo + hi) >> 1; if (batch[mid] < g) lo = mid + 1; else hi = mid; }
    int s_lo = lo;
    lo = s_lo; hi = N_NODES;
    while (lo < hi) { int mid = (lo + hi) >> 1; if (batch[mid] < g + 1) lo = mid + 1; else hi = mid; }
    int s_hi = lo;

    const int col  = tid & 127;
    const int half = tid >> 7;
    float s = 0.0f;
    for (int r = s_lo + half; r < s_hi; r += 2)
        s += h[(size_t)r * HD + col];

    __shared__ float tmp[2][HD];
    __shared__ float pool[HD];
    tmp[half][col] = s;
    __syncthreads();
    if (tid < HD) {
        float cnt = (float)(s_hi - s_lo);
        cnt = fmaxf(cnt, 1.0f);
        float v = (tmp[0][tid] + tmp[1][tid]) / cnt;
        pool[tid] = fmaxf(v, 0.0f);
    }
    __syncthreads();
    if (tid < HD) {
        float a = linb[tid];
        for (int k = 0; k < HD; ++k)
            a = fmaf(pool[k], linw[k * HD + tid], a);
        out[(size_t)g * HD + tid] = a;
    }
}

// ---------------------------------------------------------------------------
extern "C" void kernel_launch(void* const* d_in, const int* in_sizes, int n_in,
                              void* d_out, int out_size, void* d_ws, size_t ws_size,
                              hipStream_t stream)
{
    const int*   x     = (const int*)  d_in[0];
    const int*   ei    = (const int*)  d_in[1];
    const float* ew    = (const float*)d_in[2];
    const float* ea    = (const float*)d_in[3];
    const int*   batch = (const int*)  d_in[4];
    const float* emb   = (const float*)d_in[5];
    const float* ew1   = (const float*)d_in[6];
    const float* eb1   = (const float*)d_in[7];
    const float* ew2   = (const float*)d_in[8];
    const float* eb2   = (const float*)d_in[9];
    const float* nw1   = (const float*)d_in[10];
    const float* nb1   = (const float*)d_in[11];
    const float* nw2   = (const float*)d_in[12];
    const float* nb2   = (const float*)d_in[13];
    const float* linw  = (const float*)d_in[14];
    const float* linb  = (const float*)d_in[15];
    float*       out   = (float*)d_out;

    float* h   = (float*)d_ws;
    float* agg = h + (size_t)N_NODES * HD;

    embed_kernel<<<(N_NODES * (HD / 4)) / 256, 256, 0, stream>>>(x, emb, h);

    for (int l = 0; l < NLAYER; ++l) {
        hipMemsetAsync(agg, 0, (size_t)N_NODES * HD * sizeof(float), stream);
        edge_kernel<<<N_EDGES / 128, 256, 0, stream>>>(
            h, ei, ew, ea,
            ew1 + (size_t)l * 385 * HD, eb1 + (size_t)l * HD,
            ew2 + (size_t)l * HD * HD,  eb2 + (size_t)l * HD, agg);
        node_kernel<<<(N_NODES + 127) / 128, 256, 0, stream>>>(
            h, agg,
            nw1 + (size_t)l * 256 * HD, nb1 + (size_t)l * HD,
            nw2 + (size_t)l * HD * HD,  nb2 + (size_t)l * HD);
    }

    pool_kernel<<<NG, 256, 0, stream>>>(h, batch, linw, linb, out);
}

// Round 4
// 6956.753 us; speedup vs baseline: 1.7296x; 1.7296x over previous
//
#include <hip/hip_runtime.h>

#define N_NODES 50000
#define N_EDGES 800000
#define HD      128
#define NG      64
#define NLAYER  3
#define INV_CUTOFF 0.2f

__device__ __forceinline__ float silu_f(float x) {
    return x / (1.0f + __expf(-x));
}

// ---------------------------------------------------------------------------
// h[n] = emb[x[n]]   (N*H floats, float4-vectorized)
// ---------------------------------------------------------------------------
__global__ __launch_bounds__(256) void embed_kernel(
    const int* __restrict__ x, const float* __restrict__ emb,
    float* __restrict__ h)
{
    int i = blockIdx.x * 256 + threadIdx.x;      // float4 index, total N*32
    int n = i >> 5;
    int q = (i & 31) << 2;
    *(float4*)&h[(size_t)n * HD + q] =
        *(const float4*)&emb[(size_t)x[n] * HD + q];
}

// Per-thread geometry (256 threads, 128x128 tile, 8x8 micro-tile):
//   rows:  tr..tr+7,  tr = (tid>>4)<<3
//   cols:  {tcL..tcL+3} u {tcL+64..tcL+67}, tcL = (tid&15)<<2
//     -> Ws/Ys b-reads: 16 lanes hit bank-quads 0..7 twice = 2-way (free)
// As/Ys store swizzle: col-quad c4 stored at c4 ^ ((k>>2)&7)
//     -> staging writes 2-way (was 8-way), reads conflict-free.

#define YS_STORE(JB)                                                          \
    _Pragma("unroll")                                                         \
    for (int jj = 0; jj < 4; ++jj) {                                          \
        int kl = (u << 2) + jj;                                               \
        *(float4*)&Ys[kl * HD + ((trq ^ u) << 2)] =                           \
            make_float4(acc[0][(JB)+jj], acc[1][(JB)+jj],                     \
                        acc[2][(JB)+jj], acc[3][(JB)+jj]);                    \
        *(float4*)&Ys[kl * HD + (((trq + 1) ^ u) << 2)] =                     \
            make_float4(acc[4][(JB)+jj], acc[5][(JB)+jj],                     \
                        acc[6][(JB)+jj], acc[7][(JB)+jj]);                    \
    }

// ---------------------------------------------------------------------------
// Fused edge MLP + scatter:
//   m = silu(silu([h[row]|h[col]|ea|d] @ W1 + b1) @ W2 + b2); agg[row] += m
// LDS 49.5 KB -> 2 blocks/CU; staging global->reg prefetch pipelined.
// ---------------------------------------------------------------------------
__global__ __launch_bounds__(256, 2) void edge_kernel(
    const float* __restrict__ h, const int* __restrict__ ei,
    const float* __restrict__ ew, const float* __restrict__ ea,
    const float* __restrict__ W1, const float* __restrict__ b1,
    const float* __restrict__ W2, const float* __restrict__ b2,
    float* __restrict__ agg)
{
    __shared__ float Ws[32 * HD];     // 16 KB  weight K-chunk
    __shared__ float As[32 * HD];     // 16 KB  A K-chunk, [k][e] swizzled
    __shared__ float Ys[32 * HD];     // 16 KB  y1 quarter, [c&31][e] swizzled
    __shared__ int   srow[128], scol[128];
    __shared__ float sd[128];

    const int tid = threadIdx.x;
    const int e0  = blockIdx.x * 128;

    if (tid < 128) {
        int e = e0 + tid;
        srow[tid] = ei[e];
        scol[tid] = ei[N_EDGES + e];
        sd[tid]   = ew[e] * INV_CUTOFF;
    }
    __syncthreads();

    const int t15 = tid & 15;
    const int tcL = t15 << 2;          // col strip base: tcL and tcL+64
    const int tr  = (tid >> 4) << 3;   // row base
    const int trq = tr >> 2;           // even col-quad index of rows
    const int t7  = tid & 7;
    const int t8  = tid >> 3;
    const int kq  = t7 << 2;           // staging k-quad base

    // staging edge ids for this thread (fixed across chunks)
    int eA[4], rA[4], cA[4], csA[4];
#pragma unroll
    for (int i = 0; i < 4; ++i) {
        eA[i]  = t8 + (i << 5);
        rA[i]  = srow[eA[i]];
        cA[i]  = scol[eA[i]];
        csA[i] = (((eA[i] >> 2) ^ t7) << 2) | (eA[i] & 3);   // swizzled col
    }

    float4 wreg[4], areg[4];

    float acc[8][8];
#pragma unroll
    for (int i = 0; i < 8; ++i)
#pragma unroll
        for (int j = 0; j < 8; ++j) acc[i][j] = 0.0f;

    // prefetch chunk 0
#pragma unroll
    for (int i = 0; i < 4; ++i) {
        int flat = tid + (i << 8);
        wreg[i] = *(const float4*)&W1[(size_t)(flat >> 5) * HD + ((flat & 31) << 2)];
        areg[i] = *(const float4*)&h[(size_t)rA[i] * HD + kq];
    }

    // ---- GEMM1: K = 384 (12 chunks of 32); k row 384 (d term) in epilogue
#pragma unroll 1
    for (int ch = 0; ch < 12; ++ch) {
        if (ch) __syncthreads();      // prev inner reads done before overwrite
#pragma unroll
        for (int i = 0; i < 4; ++i) {
            int flat = tid + (i << 8);
            *(float4*)&Ws[(flat >> 5) * HD + ((flat & 31) << 2)] = wreg[i];
        }
#pragma unroll
        for (int i = 0; i < 4; ++i) {
            float4 v = areg[i];
            As[(kq + 0) * HD + csA[i]] = v.x;
            As[(kq + 1) * HD + csA[i]] = v.y;
            As[(kq + 2) * HD + csA[i]] = v.z;
            As[(kq + 3) * HD + csA[i]] = v.w;
        }
        __syncthreads();
        if (ch < 11) {                 // prefetch next chunk (hides under FMAs)
            int cn = ch + 1;
#pragma unroll
            for (int i = 0; i < 4; ++i) {
                int flat = tid + (i << 8);
                wreg[i] = *(const float4*)&W1[
                    (size_t)((cn << 5) + (flat >> 5)) * HD + ((flat & 31) << 2)];
                const float* src;
                if (cn < 4)      src = h  + (size_t)rA[i] * HD + (cn << 5) + kq;
                else if (cn < 8) src = h  + (size_t)cA[i] * HD + ((cn - 4) << 5) + kq;
                else             src = ea + (size_t)(e0 + eA[i]) * HD + ((cn - 8) << 5) + kq;
                areg[i] = *(const float4*)src;
            }
        }
#pragma unroll 8
        for (int k = 0; k < 32; ++k) {
            int s = (k >> 2) & 7;
            float a[8], b[8];
            *(float4*)&a[0] = *(float4*)&As[k * HD + ((trq ^ s) << 2)];
            *(float4*)&a[4] = *(float4*)&As[k * HD + (((trq + 1) ^ s) << 2)];
            *(float4*)&b[0] = *(float4*)&Ws[k * HD + tcL];
            *(float4*)&b[4] = *(float4*)&Ws[k * HD + tcL + 64];
#pragma unroll
            for (int i = 0; i < 8; ++i)
#pragma unroll
                for (int j = 0; j < 8; ++j)
                    acc[i][j] = fmaf(a[i], b[j], acc[i][j]);
        }
    }

    // ---- epilogue 1: + b1 + d*W1[384], silu -> acc (registers)
    {
        float bb[8], wd[8];
        *(float4*)&bb[0] = *(const float4*)&b1[tcL];
        *(float4*)&bb[4] = *(const float4*)&b1[tcL + 64];
        *(float4*)&wd[0] = *(const float4*)&W1[(size_t)384 * HD + tcL];
        *(float4*)&wd[4] = *(const float4*)&W1[(size_t)384 * HD + tcL + 64];
#pragma unroll
        for (int i = 0; i < 8; ++i) {
            float d = sd[tr + i];
#pragma unroll
            for (int j = 0; j < 8; ++j)
                acc[i][j] = silu_f(acc[i][j] + bb[j] + d * wd[j]);
        }
    }
    __syncthreads();                   // last GEMM1 reads done before Ys/Ws writes

    // ---- GEMM2: y2 = y1 @ W2, K = 128, four 32-col passes through Ys
    float acc2[8][8];
#pragma unroll
    for (int i = 0; i < 8; ++i)
#pragma unroll
        for (int j = 0; j < 8; ++j) acc2[i][j] = 0.0f;

    // prefetch W2 pass 0
#pragma unroll
    for (int i = 0; i < 4; ++i) {
        int flat = tid + (i << 8);
        wreg[i] = *(const float4*)&W2[(size_t)(flat >> 5) * HD + ((flat & 31) << 2)];
    }

#pragma unroll 1
    for (int p = 0; p < 4; ++p) {
        // store this pass's y1 columns [32p, 32p+32) transposed into Ys
        int sel = (p < 2) ? p : (p - 2);
        if ((t15 >> 3) == sel) {
            const int u = t15 & 7;
            if (p < 2) { YS_STORE(0) } else { YS_STORE(4) }
        }
#pragma unroll
        for (int i = 0; i < 4; ++i) {
            int flat = tid + (i << 8);
            *(float4*)&Ws[(flat >> 5) * HD + ((flat & 31) << 2)] = wreg[i];
        }
        __syncthreads();
        if (p < 3) {
#pragma unroll
            for (int i = 0; i < 4; ++i) {
                int flat = tid + (i << 8);
                wreg[i] = *(const float4*)&W2[
                    (size_t)(((p + 1) << 5) + (flat >> 5)) * HD + ((flat & 31) << 2)];
            }
        }
#pragma unroll 8
        for (int k = 0; k < 32; ++k) {
            int s = (k >> 2) & 7;
            float a[8], b[8];
            *(float4*)&a[0] = *(float4*)&Ys[k * HD + ((trq ^ s) << 2)];
            *(float4*)&a[4] = *(float4*)&Ys[k * HD + (((trq + 1) ^ s) << 2)];
            *(float4*)&b[0] = *(float4*)&Ws[k * HD + tcL];
            *(float4*)&b[4] = *(float4*)&Ws[k * HD + tcL + 64];
#pragma unroll
            for (int i = 0; i < 8; ++i)
#pragma unroll
                for (int j = 0; j < 8; ++j)
                    acc2[i][j] = fmaf(a[i], b[j], acc2[i][j]);
        }
        __syncthreads();
    }

    // ---- epilogue 2: silu, native-fp32 atomic scatter into agg[row]
    {
        float bb[8];
        *(float4*)&bb[0] = *(const float4*)&b2[tcL];
        *(float4*)&bb[4] = *(const float4*)&b2[tcL + 64];
#pragma unroll
        for (int i = 0; i < 8; ++i) {
            float* dst = agg + (size_t)srow[tr + i] * HD;
#pragma unroll
            for (int j = 0; j < 4; ++j)
                unsafeAtomicAdd(&dst[tcL + j], silu_f(acc2[i][j] + bb[j]));
#pragma unroll
            for (int j = 0; j < 4; ++j)
                unsafeAtomicAdd(&dst[tcL + 64 + j], silu_f(acc2[i][4 + j] + bb[4 + j]));
        }
    }
}

// ---------------------------------------------------------------------------
// Fused node MLP + residual: h += silu([h|agg] @ nw1 + nb1) @ nw2 + nb2
// Same structure as edge_kernel; exclusive row ownership -> no atomics.
// ---------------------------------------------------------------------------
__global__ __launch_bounds__(256, 2) void node_kernel(
    float* __restrict__ h, const float* __restrict__ agg,
    const float* __restrict__ W1, const float* __restrict__ b1,
    const float* __restrict__ W2, const float* __restrict__ b2)
{
    __shared__ float Ws[32 * HD];
    __shared__ float As[32 * HD];
    __shared__ float Ys[32 * HD];

    const int tid = threadIdx.x;
    const int n0  = blockIdx.x * 128;

    const int t15 = tid & 15;
    const int tcL = t15 << 2;
    const int tr  = (tid >> 4) << 3;
    const int trq = tr >> 2;
    const int t7  = tid & 7;
    const int t8  = tid >> 3;
    const int kq  = t7 << 2;

    int nA[4], csA[4];
#pragma unroll
    for (int i = 0; i < 4; ++i) {
        int e = t8 + (i << 5);
        int n = n0 + e;
        nA[i]  = n < N_NODES ? n : (N_NODES - 1);
        csA[i] = (((e >> 2) ^ t7) << 2) | (e & 3);
    }

    float4 wreg[4], areg[4];

    float acc[8][8];
#pragma unroll
    for (int i = 0; i < 8; ++i)
#pragma unroll
        for (int j = 0; j < 8; ++j) acc[i][j] = 0.0f;

#pragma unroll
    for (int i = 0; i < 4; ++i) {
        int flat = tid + (i << 8);
        wreg[i] = *(const float4*)&W1[(size_t)(flat >> 5) * HD + ((flat & 31) << 2)];
        areg[i] = *(const float4*)&h[(size_t)nA[i] * HD + kq];
    }

    // ---- GEMM1: K = 256 (8 chunks of 32): 0-3 from h, 4-7 from agg
#pragma unroll 1
    for (int ch = 0; ch < 8; ++ch) {
        if (ch) __syncthreads();
#pragma unroll
        for (int i = 0; i < 4; ++i) {
            int flat = tid + (i << 8);
            *(float4*)&Ws[(flat >> 5) * HD + ((flat & 31) << 2)] = wreg[i];
        }
#pragma unroll
        for (int i = 0; i < 4; ++i) {
            float4 v = areg[i];
            As[(kq + 0) * HD + csA[i]] = v.x;
            As[(kq + 1) * HD + csA[i]] = v.y;
            As[(kq + 2) * HD + csA[i]] = v.z;
            As[(kq + 3) * HD + csA[i]] = v.w;
        }
        __syncthreads();
        if (ch < 7) {
            int cn = ch + 1;
#pragma unroll
            for (int i = 0; i < 4; ++i) {
                int flat = tid + (i << 8);
                wreg[i] = *(const float4*)&W1[
                    (size_t)((cn << 5) + (flat >> 5)) * HD + ((flat & 31) << 2)];
                const float* src = (cn < 4)
                    ? h   + (size_t)nA[i] * HD + (cn << 5) + kq
                    : agg + (size_t)nA[i] * HD + ((cn - 4) << 5) + kq;
                areg[i] = *(const float4*)src;
            }
        }
#pragma unroll 8
        for (int k = 0; k < 32; ++k) {
            int s = (k >> 2) & 7;
            float a[8], b[8];
            *(float4*)&a[0] = *(float4*)&As[k * HD + ((trq ^ s) << 2)];
            *(float4*)&a[4] = *(float4*)&As[k * HD + (((trq + 1) ^ s) << 2)];
            *(float4*)&b[0] = *(float4*)&Ws[k * HD + tcL];
            *(float4*)&b[4] = *(float4*)&Ws[k * HD + tcL + 64];
#pragma unroll
            for (int i = 0; i < 8; ++i)
#pragma unroll
                for (int j = 0; j < 8; ++j)
                    acc[i][j] = fmaf(a[i], b[j], acc[i][j]);
        }
    }

    // ---- epilogue 1: silu -> acc
    {
        float bb[8];
        *(float4*)&bb[0] = *(const float4*)&b1[tcL];
        *(float4*)&bb[4] = *(const float4*)&b1[tcL + 64];
#pragma unroll
        for (int i = 0; i < 8; ++i)
#pragma unroll
            for (int j = 0; j < 8; ++j)
                acc[i][j] = silu_f(acc[i][j] + bb[j]);
    }
    __syncthreads();

    // ---- GEMM2: K = 128, four 32-col passes
    float acc2[8][8];
#pragma unroll
    for (int i = 0; i < 8; ++i)
#pragma unroll
        for (int j = 0; j < 8; ++j) acc2[i][j] = 0.0f;

#pragma unroll
    for (int i = 0; i < 4; ++i) {
        int flat = tid + (i << 8);
        wreg[i] = *(const float4*)&W2[(size_t)(flat >> 5) * HD + ((flat & 31) << 2)];
    }

#pragma unroll 1
    for (int p = 0; p < 4; ++p) {
        int sel = (p < 2) ? p : (p - 2);
        if ((t15 >> 3) == sel) {
            const int u = t15 & 7;
            if (p < 2) { YS_STORE(0) } else { YS_STORE(4) }
        }
#pragma unroll
        for (int i = 0; i < 4; ++i) {
            int flat = tid + (i << 8);
            *(float4*)&Ws[(flat >> 5) * HD + ((flat & 31) << 2)] = wreg[i];
        }
        __syncthreads();
        if (p < 3) {
#pragma unroll
            for (int i = 0; i < 4; ++i) {
                int flat = tid + (i << 8);
                wreg[i] = *(const float4*)&W2[
                    (size_t)(((p + 1) << 5) + (flat >> 5)) * HD + ((flat & 31) << 2)];
            }
        }
#pragma unroll 8
        for (int k = 0; k < 32; ++k) {
            int s = (k >> 2) & 7;
            float a[8], b[8];
            *(float4*)&a[0] = *(float4*)&Ys[k * HD + ((trq ^ s) << 2)];
            *(float4*)&a[4] = *(float4*)&Ys[k * HD + (((trq + 1) ^ s) << 2)];
            *(float4*)&b[0] = *(float4*)&Ws[k * HD + tcL];
            *(float4*)&b[4] = *(float4*)&Ws[k * HD + tcL + 64];
#pragma unroll
            for (int i = 0; i < 8; ++i)
#pragma unroll
                for (int j = 0; j < 8; ++j)
                    acc2[i][j] = fmaf(a[i], b[j], acc2[i][j]);
        }
        __syncthreads();
    }

    // ---- epilogue 2: residual add (exclusive ownership, plain RMW)
    {
        float bb[8];
        *(float4*)&bb[0] = *(const float4*)&b2[tcL];
        *(float4*)&bb[4] = *(const float4*)&b2[tcL + 64];
#pragma unroll
        for (int i = 0; i < 8; ++i) {
            int n = n0 + tr + i;
            if (n < N_NODES) {
                float* dst = h + (size_t)n * HD;
                float4 o0 = *(float4*)&dst[tcL];
                float4 o1 = *(float4*)&dst[tcL + 64];
                o0.x += acc2[i][0] + bb[0];
                o0.y += acc2[i][1] + bb[1];
                o0.z += acc2[i][2] + bb[2];
                o0.w += acc2[i][3] + bb[3];
                o1.x += acc2[i][4] + bb[4];
                o1.y += acc2[i][5] + bb[5];
                o1.z += acc2[i][6] + bb[6];
                o1.w += acc2[i][7] + bb[7];
                *(float4*)&dst[tcL]      = o0;
                *(float4*)&dst[tcL + 64] = o1;
            }
        }
    }
}

// ---------------------------------------------------------------------------
// Per-graph mean pool (batch sorted) -> relu -> @ linw + linb
// ---------------------------------------------------------------------------
__global__ __launch_bounds__(256) void pool_kernel(
    const float* __restrict__ h, const int* __restrict__ batch,
    const float* __restrict__ linw, const float* __restrict__ linb,
    float* __restrict__ out)
{
    const int g   = blockIdx.x;
    const int tid = threadIdx.x;

    int lo = 0, hi = N_NODES;
    while (lo < hi) { int mid = (lo + hi) >> 1; if (batch[mid] < g) lo = mid + 1; else hi = mid; }
    int s_lo = lo;
    lo = s_lo; hi = N_NODES;
    while (lo < hi) { int mid = (lo + hi) >> 1; if (batch[mid] < g + 1) lo = mid + 1; else hi = mid; }
    int s_hi = lo;

    const int col  = tid & 127;
    const int half = tid >> 7;
    float s = 0.0f;
    for (int r = s_lo + half; r < s_hi; r += 2)
        s += h[(size_t)r * HD + col];

    __shared__ float tmp[2][HD];
    __shared__ float pool[HD];
    tmp[half][col] = s;
    __syncthreads();
    if (tid < HD) {
        float cnt = (float)(s_hi - s_lo);
        cnt = fmaxf(cnt, 1.0f);
        float v = (tmp[0][tid] + tmp[1][tid]) / cnt;
        pool[tid] = fmaxf(v, 0.0f);
    }
    __syncthreads();
    if (tid < HD) {
        float a = linb[tid];
        for (int k = 0; k < HD; ++k)
            a = fmaf(pool[k], linw[k * HD + tid], a);
        out[(size_t)g * HD + tid] = a;
    }
}

// ---------------------------------------------------------------------------
extern "C" void kernel_launch(void* const* d_in, const int* in_sizes, int n_in,
                              void* d_out, int out_size, void* d_ws, size_t ws_size,
                              hipStream_t stream)
{
    const int*   x     = (const int*)  d_in[0];
    const int*   ei    = (const int*)  d_in[1];
    const float* ew    = (const float*)d_in[2];
    const float* ea    = (const float*)d_in[3];
    const int*   batch = (const int*)  d_in[4];
    const float* emb   = (const float*)d_in[5];
    const float* ew1   = (const float*)d_in[6];
    const float* eb1   = (const float*)d_in[7];
    const float* ew2   = (const float*)d_in[8];
    const float* eb2   = (const float*)d_in[9];
    const float* nw1   = (const float*)d_in[10];
    const float* nb1   = (const float*)d_in[11];
    const float* nw2   = (const float*)d_in[12];
    const float* nb2   = (const float*)d_in[13];
    const float* linw  = (const float*)d_in[14];
    const float* linb  = (const float*)d_in[15];
    float*       out   = (float*)d_out;

    float* h   = (float*)d_ws;
    float* agg = h + (size_t)N_NODES * HD;

    embed_kernel<<<(N_NODES * (HD / 4)) / 256, 256, 0, stream>>>(x, emb, h);

    for (int l = 0; l < NLAYER; ++l) {
        hipMemsetAsync(agg, 0, (size_t)N_NODES * HD * sizeof(float), stream);
        edge_kernel<<<N_EDGES / 128, 256, 0, stream>>>(
            h, ei, ew, ea,
            ew1 + (size_t)l * 385 * HD, eb1 + (size_t)l * HD,
            ew2 + (size_t)l * HD * HD,  eb2 + (size_t)l * HD, agg);
        node_kernel<<<(N_NODES + 127) / 128, 256, 0, stream>>>(
            h, agg,
            nw1 + (size_t)l * 256 * HD, nb1 + (size_t)l * HD,
            nw2 + (size_t)l * HD * HD,  nb2 + (size_t)l * HD);
    }

    pool_kernel<<<NG, 256, 0, stream>>>(h, batch, linw, linb, out);
}

// Round 6
// 5773.510 us; speedup vs baseline: 2.0840x; 1.2049x over previous
//
#include <hip/hip_runtime.h>

#define N_NODES 50000
#define N_EDGES 800000
#define HD      128
#define NG      64
#define NLAYER  3
#define INV_CUTOFF 0.2f

__device__ __forceinline__ float silu_f(float x) {
    return x / (1.0f + __expf(-x));
}

// ---------------------------------------------------------------------------
// Counting sort of edges by destination row (ei[0][e]).
// S1: histogram  S2: single-block exclusive scan (in-place)  S3: scatter perm
// ---------------------------------------------------------------------------
__global__ __launch_bounds__(256) void hist_kernel(
    const int* __restrict__ ei, int* __restrict__ cnt)
{
    int e = blockIdx.x * 256 + threadIdx.x;
    if (e < N_EDGES) atomicAdd(&cnt[ei[e]], 1);
}

__global__ __launch_bounds__(1024) void scan_kernel(int* __restrict__ cnt)
{
    __shared__ int buf[1024];
    __shared__ int carry_s;
    const int tid = threadIdx.x;
    if (tid == 0) carry_s = 0;
    __syncthreads();
    for (int base = 0; base < N_NODES; base += 1024) {
        int idx = base + tid;
        int v = (idx < N_NODES) ? cnt[idx] : 0;
        buf[tid] = v;
        __syncthreads();
        for (int off = 1; off < 1024; off <<= 1) {
            int t = (tid >= off) ? buf[tid - off] : 0;
            __syncthreads();
            buf[tid] += t;
            __syncthreads();
        }
        int incl  = buf[tid];
        int carry = carry_s;
        __syncthreads();
        if (idx < N_NODES) cnt[idx] = carry + incl - v;   // exclusive
        if (tid == 1023) carry_s = carry + buf[1023];
        __syncthreads();
    }
}

__global__ __launch_bounds__(256) void scatter_kernel(
    const int* __restrict__ ei, int* __restrict__ cnt, int* __restrict__ perm)
{
    int e = blockIdx.x * 256 + threadIdx.x;
    if (e < N_EDGES) {
        int p = atomicAdd(&cnt[ei[e]], 1);
        perm[p] = e;
    }
}

// ---------------------------------------------------------------------------
// h[n] = emb[x[n]]   (N*H floats, float4-vectorized)
// ---------------------------------------------------------------------------
__global__ __launch_bounds__(256) void embed_kernel(
    const int* __restrict__ x, const float* __restrict__ emb,
    float* __restrict__ h)
{
    int i = blockIdx.x * 256 + threadIdx.x;      // float4 index, total N*32
    int n = i >> 5;
    int q = (i & 31) << 2;
    *(float4*)&h[(size_t)n * HD + q] =
        *(const float4*)&emb[(size_t)x[n] * HD + q];
}

// Per-thread geometry (256 threads, 128x128 tile, 8x8 micro-tile):
//   rows:  tr..tr+7,  tr = (tid>>4)<<3
//   cols:  {tcL..tcL+3} u {tcL+64..tcL+67}, tcL = (tid&15)<<2
//     -> Ws/Ys b-reads: 16 lanes hit bank-quads 0..7 twice = 2-way (free)
// As/Ys store swizzle: col-quad c4 stored at c4 ^ ((k>>2)&7)
//     -> staging writes 2-way (was 8-way), reads conflict-free (r4: SQ_LDS_BANK_CONFLICT=0)

#define YS_STORE(JB)                                                          \
    _Pragma("unroll")                                                         \
    for (int jj = 0; jj < 4; ++jj) {                                          \
        int kl = (u << 2) + jj;                                               \
        *(float4*)&Ys[kl * HD + ((trq ^ u) << 2)] =                           \
            make_float4(acc[0][(JB)+jj], acc[1][(JB)+jj],                     \
                        acc[2][(JB)+jj], acc[3][(JB)+jj]);                    \
        *(float4*)&Ys[kl * HD + (((trq + 1) ^ u) << 2)] =                     \
            make_float4(acc[4][(JB)+jj], acc[5][(JB)+jj],                     \
                        acc[6][(JB)+jj], acc[7][(JB)+jj]);                    \
    }

// ---------------------------------------------------------------------------
// Fused edge MLP + scatter, operating on row-sorted edge order (perm):
//   m = silu(silu([h[row]|h[col]|ea|d] @ W1 + b1) @ W2 + b2); agg[row] += m
// Sorted rows -> h-gathers L1-hot, atomics line-local; run-length merge in
// the epilogue cuts atomic count ~4-8x. LDS 51.2 KB -> 3 blocks/CU.
// ---------------------------------------------------------------------------
__global__ __launch_bounds__(256, 3) void edge_kernel(
    const float* __restrict__ h, const int* __restrict__ ei,
    const float* __restrict__ ew, const float* __restrict__ ea,
    const int* __restrict__ perm,
    const float* __restrict__ W1, const float* __restrict__ b1,
    const float* __restrict__ W2, const float* __restrict__ b2,
    float* __restrict__ agg)
{
    __shared__ float Ws[32 * HD];     // 16 KB  weight K-chunk
    __shared__ float As[32 * HD];     // 16 KB  A K-chunk, [k][e] swizzled
    __shared__ float Ys[32 * HD];     // 16 KB  y1 quarter, [c&31][e] swizzled
    __shared__ int   srow[128], scol[128], sper[128];
    __shared__ float sd[128];

    const int tid = threadIdx.x;

    // bijective XCD swizzle (nwg=6250 = 8*781+2): consecutive tiles (which
    // share sorted rows) stay on one XCD's L2.
    const int nwg = N_EDGES / 128;
    const int q8  = nwg >> 3, r8 = nwg & 7;
    int xcd = blockIdx.x & 7, sub = blockIdx.x >> 3;
    int bid = (xcd < r8 ? xcd * (q8 + 1) : r8 * (q8 + 1) + (xcd - r8) * q8) + sub;
    const int e0 = bid * 128;

    if (tid < 128) {
        int e = perm[e0 + tid];
        sper[tid] = e;
        srow[tid] = ei[e];
        scol[tid] = ei[N_EDGES + e];
        sd[tid]   = ew[e] * INV_CUTOFF;
    }
    __syncthreads();

    const int t15 = tid & 15;
    const int tcL = t15 << 2;          // col strip base: tcL and tcL+64
    const int tr  = (tid >> 4) << 3;   // row base
    const int trq = tr >> 2;           // even col-quad index of rows
    const int t7  = tid & 7;
    const int t8  = tid >> 3;
    const int kq  = t7 << 2;           // staging k-quad base

    // staging edge slots for this thread (fixed across chunks)
    int eA[4], rA[4], cA[4], csA[4], eO[4];
#pragma unroll
    for (int i = 0; i < 4; ++i) {
        eA[i]  = t8 + (i << 5);
        rA[i]  = srow[eA[i]];
        cA[i]  = scol[eA[i]];
        eO[i]  = sper[eA[i]];
        csA[i] = (((eA[i] >> 2) ^ t7) << 2) | (eA[i] & 3);   // swizzled col
    }

    float4 wreg[4], areg[4];

    float acc[8][8];
#pragma unroll
    for (int i = 0; i < 8; ++i)
#pragma unroll
        for (int j = 0; j < 8; ++j) acc[i][j] = 0.0f;

    // prefetch chunk 0
#pragma unroll
    for (int i = 0; i < 4; ++i) {
        int flat = tid + (i << 8);
        wreg[i] = *(const float4*)&W1[(size_t)(flat >> 5) * HD + ((flat & 31) << 2)];
        areg[i] = *(const float4*)&h[(size_t)rA[i] * HD + kq];
    }

    // ---- GEMM1: K = 384 (12 chunks of 32); k row 384 (d term) in epilogue
#pragma unroll 1
    for (int ch = 0; ch < 12; ++ch) {
        if (ch) __syncthreads();      // prev inner reads done before overwrite
#pragma unroll
        for (int i = 0; i < 4; ++i) {
            int flat = tid + (i << 8);
            *(float4*)&Ws[(flat >> 5) * HD + ((flat & 31) << 2)] = wreg[i];
        }
#pragma unroll
        for (int i = 0; i < 4; ++i) {
            float4 v = areg[i];
            As[(kq + 0) * HD + csA[i]] = v.x;
            As[(kq + 1) * HD + csA[i]] = v.y;
            As[(kq + 2) * HD + csA[i]] = v.z;
            As[(kq + 3) * HD + csA[i]] = v.w;
        }
        __syncthreads();
        if (ch < 11) {                 // prefetch next chunk (hides under FMAs)
            int cn = ch + 1;
#pragma unroll
            for (int i = 0; i < 4; ++i) {
                int flat = tid + (i << 8);
                wreg[i] = *(const float4*)&W1[
                    (size_t)((cn << 5) + (flat >> 5)) * HD + ((flat & 31) << 2)];
                const float* src;
                if (cn < 4)      src = h  + (size_t)rA[i] * HD + (cn << 5) + kq;
                else if (cn < 8) src = h  + (size_t)cA[i] * HD + ((cn - 4) << 5) + kq;
                else             src = ea + (size_t)eO[i] * HD + ((cn - 8) << 5) + kq;
                areg[i] = *(const float4*)src;
            }
        }
#pragma unroll 8
        for (int k = 0; k < 32; ++k) {
            int s = (k >> 2) & 7;
            float a[8], b[8];
            *(float4*)&a[0] = *(float4*)&As[k * HD + ((trq ^ s) << 2)];
            *(float4*)&a[4] = *(float4*)&As[k * HD + (((trq + 1) ^ s) << 2)];
            *(float4*)&b[0] = *(float4*)&Ws[k * HD + tcL];
            *(float4*)&b[4] = *(float4*)&Ws[k * HD + tcL + 64];
#pragma unroll
            for (int i = 0; i < 8; ++i)
#pragma unroll
                for (int j = 0; j < 8; ++j)
                    acc[i][j] = fmaf(a[i], b[j], acc[i][j]);
        }
    }

    // ---- epilogue 1: + b1 + d*W1[384], silu -> acc (registers)
    {
        float bb[8], wd[8];
        *(float4*)&bb[0] = *(const float4*)&b1[tcL];
        *(float4*)&bb[4] = *(const float4*)&b1[tcL + 64];
        *(float4*)&wd[0] = *(const float4*)&W1[(size_t)384 * HD + tcL];
        *(float4*)&wd[4] = *(const float4*)&W1[(size_t)384 * HD + tcL + 64];
#pragma unroll
        for (int i = 0; i < 8; ++i) {
            float d = sd[tr + i];
#pragma unroll
            for (int j = 0; j < 8; ++j)
                acc[i][j] = silu_f(acc[i][j] + bb[j] + d * wd[j]);
        }
    }
    __syncthreads();                   // last GEMM1 reads done before Ys/Ws writes

    // ---- GEMM2: y2 = y1 @ W2, K = 128, four 32-col passes through Ys
    float acc2[8][8];
#pragma unroll
    for (int i = 0; i < 8; ++i)
#pragma unroll
        for (int j = 0; j < 8; ++j) acc2[i][j] = 0.0f;

    // prefetch W2 pass 0
#pragma unroll
    for (int i = 0; i < 4; ++i) {
        int flat = tid + (i << 8);
        wreg[i] = *(const float4*)&W2[(size_t)(flat >> 5) * HD + ((flat & 31) << 2)];
    }

#pragma unroll 1
    for (int p = 0; p < 4; ++p) {
        // store this pass's y1 columns [32p, 32p+32) transposed into Ys
        int sel = (p < 2) ? p : (p - 2);
        if ((t15 >> 3) == sel) {
            const int u = t15 & 7;
            if (p < 2) { YS_STORE(0) } else { YS_STORE(4) }
        }
#pragma unroll
        for (int i = 0; i < 4; ++i) {
            int flat = tid + (i << 8);
            *(float4*)&Ws[(flat >> 5) * HD + ((flat & 31) << 2)] = wreg[i];
        }
        __syncthreads();
        if (p < 3) {
#pragma unroll
            for (int i = 0; i < 4; ++i) {
                int flat = tid + (i << 8);
                wreg[i] = *(const float4*)&W2[
                    (size_t)(((p + 1) << 5) + (flat >> 5)) * HD + ((flat & 31) << 2)];
            }
        }
#pragma unroll 8
        for (int k = 0; k < 32; ++k) {
            int s = (k >> 2) & 7;
            float a[8], b[8];
            *(float4*)&a[0] = *(float4*)&Ys[k * HD + ((trq ^ s) << 2)];
            *(float4*)&a[4] = *(float4*)&Ys[k * HD + (((trq + 1) ^ s) << 2)];
            *(float4*)&b[0] = *(float4*)&Ws[k * HD + tcL];
            *(float4*)&b[4] = *(float4*)&Ws[k * HD + tcL + 64];
#pragma unroll
            for (int i = 0; i < 8; ++i)
#pragma unroll
                for (int j = 0; j < 8; ++j)
                    acc2[i][j] = fmaf(a[i], b[j], acc2[i][j]);
        }
        __syncthreads();
    }

    // ---- epilogue 2: silu, run-length merge over sorted rows, atomic scatter
    {
        float bb[8];
        *(float4*)&bb[0] = *(const float4*)&b2[tcL];
        *(float4*)&bb[4] = *(const float4*)&b2[tcL + 64];
        float sum[8];
        int cur_row = srow[tr];
#pragma unroll
        for (int j = 0; j < 8; ++j) sum[j] = silu_f(acc2[0][j] + bb[j]);
#pragma unroll
        for (int i = 1; i < 8; ++i) {            // fully unrolled: acc2 static
            int rr = srow[tr + i];
            if (rr != cur_row) {
                float* dst = agg + (size_t)cur_row * HD;
#pragma unroll
                for (int j = 0; j < 4; ++j)
                    unsafeAtomicAdd(&dst[tcL + j], sum[j]);
#pragma unroll
                for (int j = 0; j < 4; ++j)
                    unsafeAtomicAdd(&dst[tcL + 64 + j], sum[4 + j]);
                cur_row = rr;
#pragma unroll
                for (int j = 0; j < 8; ++j) sum[j] = silu_f(acc2[i][j] + bb[j]);
            } else {
#pragma unroll
                for (int j = 0; j < 8; ++j) sum[j] += silu_f(acc2[i][j] + bb[j]);
            }
        }
        float* dst = agg + (size_t)cur_row * HD;
#pragma unroll
        for (int j = 0; j < 4; ++j)
            unsafeAtomicAdd(&dst[tcL + j], sum[j]);
#pragma unroll
        for (int j = 0; j < 4; ++j)
            unsafeAtomicAdd(&dst[tcL + 64 + j], sum[4 + j]);
    }
}

// ---------------------------------------------------------------------------
// Fused node MLP + residual: h += silu([h|agg] @ nw1 + nb1) @ nw2 + nb2
// Same structure as edge_kernel; exclusive row ownership -> no atomics.
// ---------------------------------------------------------------------------
__global__ __launch_bounds__(256, 3) void node_kernel(
    float* __restrict__ h, const float* __restrict__ agg,
    const float* __restrict__ W1, const float* __restrict__ b1,
    const float* __restrict__ W2, const float* __restrict__ b2)
{
    __shared__ float Ws[32 * HD];
    __shared__ float As[32 * HD];
    __shared__ float Ys[32 * HD];

    const int tid = threadIdx.x;
    const int n0  = blockIdx.x * 128;

    const int t15 = tid & 15;
    const int tcL = t15 << 2;
    const int tr  = (tid >> 4) << 3;
    const int trq = tr >> 2;
    const int t7  = tid & 7;
    const int t8  = tid >> 3;
    const int kq  = t7 << 2;

    int nA[4], csA[4];
#pragma unroll
    for (int i = 0; i < 4; ++i) {
        int e = t8 + (i << 5);
        int n = n0 + e;
        nA[i]  = n < N_NODES ? n : (N_NODES - 1);
        csA[i] = (((e >> 2) ^ t7) << 2) | (e & 3);
    }

    float4 wreg[4], areg[4];

    float acc[8][8];
#pragma unroll
    for (int i = 0; i < 8; ++i)
#pragma unroll
        for (int j = 0; j < 8; ++j) acc[i][j] = 0.0f;

#pragma unroll
    for (int i = 0; i < 4; ++i) {
        int flat = tid + (i << 8);
        wreg[i] = *(const float4*)&W1[(size_t)(flat >> 5) * HD + ((flat & 31) << 2)];
        areg[i] = *(const float4*)&h[(size_t)nA[i] * HD + kq];
    }

    // ---- GEMM1: K = 256 (8 chunks of 32): 0-3 from h, 4-7 from agg
#pragma unroll 1
    for (int ch = 0; ch < 8; ++ch) {
        if (ch) __syncthreads();
#pragma unroll
        for (int i = 0; i < 4; ++i) {
            int flat = tid + (i << 8);
            *(float4*)&Ws[(flat >> 5) * HD + ((flat & 31) << 2)] = wreg[i];
        }
#pragma unroll
        for (int i = 0; i < 4; ++i) {
            float4 v = areg[i];
            As[(kq + 0) * HD + csA[i]] = v.x;
            As[(kq + 1) * HD + csA[i]] = v.y;
            As[(kq + 2) * HD + csA[i]] = v.z;
            As[(kq + 3) * HD + csA[i]] = v.w;
        }
        __syncthreads();
        if (ch < 7) {
            int cn = ch + 1;
#pragma unroll
            for (int i = 0; i < 4; ++i) {
                int flat = tid + (i << 8);
                wreg[i] = *(const float4*)&W1[
                    (size_t)((cn << 5) + (flat >> 5)) * HD + ((flat & 31) << 2)];
                const float* src = (cn < 4)
                    ? h   + (size_t)nA[i] * HD + (cn << 5) + kq
                    : agg + (size_t)nA[i] * HD + ((cn - 4) << 5) + kq;
                areg[i] = *(const float4*)src;
            }
        }
#pragma unroll 8
        for (int k = 0; k < 32; ++k) {
            int s = (k >> 2) & 7;
            float a[8], b[8];
            *(float4*)&a[0] = *(float4*)&As[k * HD + ((trq ^ s) << 2)];
            *(float4*)&a[4] = *(float4*)&As[k * HD + (((trq + 1) ^ s) << 2)];
            *(float4*)&b[0] = *(float4*)&Ws[k * HD + tcL];
            *(float4*)&b[4] = *(float4*)&Ws[k * HD + tcL + 64];
#pragma unroll
            for (int i = 0; i < 8; ++i)
#pragma unroll
                for (int j = 0; j < 8; ++j)
                    acc[i][j] = fmaf(a[i], b[j], acc[i][j]);
        }
    }

    // ---- epilogue 1: silu -> acc
    {
        float bb[8];
        *(float4*)&bb[0] = *(const float4*)&b1[tcL];
        *(float4*)&bb[4] = *(const float4*)&b1[tcL + 64];
#pragma unroll
        for (int i = 0; i < 8; ++i)
#pragma unroll
            for (int j = 0; j < 8; ++j)
                acc[i][j] = silu_f(acc[i][j] + bb[j]);
    }
    __syncthreads();

    // ---- GEMM2: K = 128, four 32-col passes
    float acc2[8][8];
#pragma unroll
    for (int i = 0; i < 8; ++i)
#pragma unroll
        for (int j = 0; j < 8; ++j) acc2[i][j] = 0.0f;

#pragma unroll
    for (int i = 0; i < 4; ++i) {
        int flat = tid + (i << 8);
        wreg[i] = *(const float4*)&W2[(size_t)(flat >> 5) * HD + ((flat & 31) << 2)];
    }

#pragma unroll 1
    for (int p = 0; p < 4; ++p) {
        int sel = (p < 2) ? p : (p - 2);
        if ((t15 >> 3) == sel) {
            const int u = t15 & 7;
            if (p < 2) { YS_STORE(0) } else { YS_STORE(4) }
        }
#pragma unroll
        for (int i = 0; i < 4; ++i) {
            int flat = tid + (i << 8);
            *(float4*)&Ws[(flat >> 5) * HD + ((flat & 31) << 2)] = wreg[i];
        }
        __syncthreads();
        if (p < 3) {
#pragma unroll
            for (int i = 0; i < 4; ++i) {
                int flat = tid + (i << 8);
                wreg[i] = *(const float4*)&W2[
                    (size_t)(((p + 1) << 5) + (flat >> 5)) * HD + ((flat & 31) << 2)];
            }
        }
#pragma unroll 8
        for (int k = 0; k < 32; ++k) {
            int s = (k >> 2) & 7;
            float a[8], b[8];
            *(float4*)&a[0] = *(float4*)&Ys[k * HD + ((trq ^ s) << 2)];
            *(float4*)&a[4] = *(float4*)&Ys[k * HD + (((trq + 1) ^ s) << 2)];
            *(float4*)&b[0] = *(float4*)&Ws[k * HD + tcL];
            *(float4*)&b[4] = *(float4*)&Ws[k * HD + tcL + 64];
#pragma unroll
            for (int i = 0; i < 8; ++i)
#pragma unroll
                for (int j = 0; j < 8; ++j)
                    acc2[i][j] = fmaf(a[i], b[j], acc2[i][j]);
        }
        __syncthreads();
    }

    // ---- epilogue 2: residual add (exclusive ownership, plain RMW)
    {
        float bb[8];
        *(float4*)&bb[0] = *(const float4*)&b2[tcL];
        *(float4*)&bb[4] = *(const float4*)&b2[tcL + 64];
#pragma unroll
        for (int i = 0; i < 8; ++i) {
            int n = n0 + tr + i;
            if (n < N_NODES) {
                float* dst = h + (size_t)n * HD;
                float4 o0 = *(float4*)&dst[tcL];
                float4 o1 = *(float4*)&dst[tcL + 64];
                o0.x += acc2[i][0] + bb[0];
                o0.y += acc2[i][1] + bb[1];
                o0.z += acc2[i][2] + bb[2];
                o0.w += acc2[i][3] + bb[3];
                o1.x += acc2[i][4] + bb[4];
                o1.y += acc2[i][5] + bb[5];
                o1.z += acc2[i][6] + bb[6];
                o1.w += acc2[i][7] + bb[7];
                *(float4*)&dst[tcL]      = o0;
                *(float4*)&dst[tcL + 64] = o1;
            }
        }
    }
}

// ---------------------------------------------------------------------------
// Per-graph mean pool (batch sorted) -> relu -> @ linw + linb
// ---------------------------------------------------------------------------
__global__ __launch_bounds__(256) void pool_kernel(
    const float* __restrict__ h, const int* __restrict__ batch,
    const float* __restrict__ linw, const float* __restrict__ linb,
    float* __restrict__ out)
{
    const int g   = blockIdx.x;
    const int tid = threadIdx.x;

    int lo = 0, hi = N_NODES;
    while (lo < hi) { int mid = (lo + hi) >> 1; if (batch[mid] < g) lo = mid + 1; else hi = mid; }
    int s_lo = lo;
    lo = s_lo; hi = N_NODES;
    while (lo < hi) { int mid = (lo + hi) >> 1; if (batch[mid] < g + 1) lo = mid + 1; else hi = mid; }
    int s_hi = lo;

    const int col  = tid & 127;
    const int half = tid >> 7;
    float s = 0.0f;
    for (int r = s_lo + half; r < s_hi; r += 2)
        s += h[(size_t)r * HD + col];

    __shared__ float tmp[2][HD];
    __shared__ float pool[HD];
    tmp[half][col] = s;
    __syncthreads();
    if (tid < HD) {
        float cnt = (float)(s_hi - s_lo);
        cnt = fmaxf(cnt, 1.0f);
        float v = (tmp[0][tid] + tmp[1][tid]) / cnt;
        pool[tid] = fmaxf(v, 0.0f);
    }
    __syncthreads();
    if (tid < HD) {
        float a = linb[tid];
        for (int k = 0; k < HD; ++k)
            a = fmaf(pool[k], linw[k * HD + tid], a);
        out[(size_t)g * HD + tid] = a;
    }
}

// ---------------------------------------------------------------------------
extern "C" void kernel_launch(void* const* d_in, const int* in_sizes, int n_in,
                              void* d_out, int out_size, void* d_ws, size_t ws_size,
                              hipStream_t stream)
{
    const int*   x     = (const int*)  d_in[0];
    const int*   ei    = (const int*)  d_in[1];
    const float* ew    = (const float*)d_in[2];
    const float* ea    = (const float*)d_in[3];
    const int*   batch = (const int*)  d_in[4];
    const float* emb   = (const float*)d_in[5];
    const float* ew1   = (const float*)d_in[6];
    const float* eb1   = (const float*)d_in[7];
    const float* ew2   = (const float*)d_in[8];
    const float* eb2   = (const float*)d_in[9];
    const float* nw1   = (const float*)d_in[10];
    const float* nb1   = (const float*)d_in[11];
    const float* nw2   = (const float*)d_in[12];
    const float* nb2   = (const float*)d_in[13];
    const float* linw  = (const float*)d_in[14];
    const float* linb  = (const float*)d_in[15];
    float*       out   = (float*)d_out;

    // workspace layout: h | agg | perm | cnt   (~54.6 MB)
    float* h    = (float*)d_ws;
    float* agg  = h + (size_t)N_NODES * HD;
    int*   perm = (int*)(agg + (size_t)N_NODES * HD);
    int*   cnt  = perm + N_EDGES;

    // edge sort by destination row (rebuilt every call; ws is re-poisoned)
    hipMemsetAsync(cnt, 0, (size_t)N_NODES * sizeof(int), stream);
    hist_kernel<<<(N_EDGES + 255) / 256, 256, 0, stream>>>(ei, cnt);
    scan_kernel<<<1, 1024, 0, stream>>>(cnt);
    scatter_kernel<<<(N_EDGES + 255) / 256, 256, 0, stream>>>(ei, cnt, perm);

    embed_kernel<<<(N_NODES * (HD / 4)) / 256, 256, 0, stream>>>(x, emb, h);

    for (int l = 0; l < NLAYER; ++l) {
        hipMemsetAsync(agg, 0, (size_t)N_NODES * HD * sizeof(float), stream);
        edge_kernel<<<N_EDGES / 128, 256, 0, stream>>>(
            h, ei, ew, ea, perm,
            ew1 + (size_t)l * 385 * HD, eb1 + (size_t)l * HD,
            ew2 + (size_t)l * HD * HD,  eb2 + (size_t)l * HD, agg);
        node_kernel<<<(N_NODES + 127) / 128, 256, 0, stream>>>(
            h, agg,
            nw1 + (size_t)l * 256 * HD, nb1 + (size_t)l * HD,
            nw2 + (size_t)l * HD * HD,  nb2 + (size_t)l * HD);
    }

    pool_kernel<<<NG, 256, 0, stream>>>(h, batch, linw, linb, out);
}